// Round 1
// baseline (63.089 us; speedup 1.0000x reference)
//
#include <hip/hip_runtime.h>
#include <hip/hip_bf16.h>

// Problem constants (from reference)
#define NN 32
#define K_TOTAL 4
#define RESOLUTION 64
#define KNOTS (NN * RESOLUTION + 1)   // 2049
#define BATCH 256
#define HEAD 2048                      // KNOTS - 1; last c_eff element never contributes
#define OUT_TOTAL (BATCH * NN * K_TOTAL)  // 32768

// Kernel A: one block of 256 threads builds fp64 prefix sums
//   P1[m] = sum_{j<m} c_relu[j]
//   P2[m] = sum_{j<m} j * c_relu[j]
// for m = 0..2048, stored in d_ws as [P1(2049 doubles) | P2(2049 doubles)].
__global__ __launch_bounds__(256) void scan_kernel(const float* __restrict__ c_relu,
                                                   double* __restrict__ P) {
    __shared__ double s1[256];
    __shared__ double s2[256];
    const int t = threadIdx.x;
    const int base = t * 8;   // 256 threads * 8 = 2048 elements

    float c[8];
#pragma unroll
    for (int i = 0; i < 8; ++i) c[i] = c_relu[base + i];

    // exclusive prefix within this thread's chunk
    double pre1[8], pre2[8];
    double l1 = 0.0, l2 = 0.0;
#pragma unroll
    for (int i = 0; i < 8; ++i) {
        pre1[i] = l1;
        pre2[i] = l2;
        l1 += (double)c[i];
        l2 += (double)(base + i) * (double)c[i];
    }
    s1[t] = l1;
    s2[t] = l2;

    // Hillis-Steele inclusive scan across the 256 chunk totals
    for (int off = 1; off < 256; off <<= 1) {
        __syncthreads();
        double a1 = 0.0, a2 = 0.0;
        if (t >= off) { a1 = s1[t - off]; a2 = s2[t - off]; }
        __syncthreads();
        if (t >= off) { s1[t] += a1; s2[t] += a2; }
    }
    __syncthreads();

    const double off1 = (t == 0) ? 0.0 : s1[t - 1];
    const double off2 = (t == 0) ? 0.0 : s2[t - 1];

    double* __restrict__ P1 = P;
    double* __restrict__ P2 = P + KNOTS;
#pragma unroll
    for (int i = 0; i < 8; ++i) {
        P1[base + i] = off1 + pre1[i];
        P2[base + i] = off2 + pre2[i];
    }
    if (t == 255) {
        P1[HEAD] = s1[255];
        P2[HEAD] = s2[255];
    }
}

// Kernel B: one thread per output element.
// out[b,n,k] = x*P1[m] - P2[m]/64 + init_val,  x = mod(t[b,k]-n, 32), m = #{j: j < 64x}
__global__ __launch_bounds__(256) void eval_kernel(const float* __restrict__ t_k,
                                                   const float* __restrict__ init_val,
                                                   const double* __restrict__ P,
                                                   float* __restrict__ out) {
    const int o = blockIdx.x * blockDim.x + threadIdx.x;   // 0..32767
    const int k = o & (K_TOTAL - 1);
    const int n = (o >> 2) & (NN - 1);
    const int b = o >> 7;

    const float t = t_k[(b << 2) | k];
    // replicate reference fp32 rounding: fmod(t-n,32) is exact (|t-n|<32),
    // then +32 correction for negative values (single rounding, same as np.remainder)
    float r = t - (float)n;
    if (r < 0.0f) r += 32.0f;

    // m = count of integers j in [0,2048] with j < 64*r  (64*r exact in fp64)
    const double d = (double)r * 64.0;
    int m = (int)d;
    if ((double)m < d) ++m;
    if (m > HEAD) m = HEAD;   // safety clamp (r <= 32 -> d <= 2048)

    const double* __restrict__ P1 = P;
    const double* __restrict__ P2 = P + KNOTS;
    const double phi = (double)r * P1[m] - P2[m] * 0.015625 + (double)init_val[0];
    out[o] = (float)phi;
}

extern "C" void kernel_launch(void* const* d_in, const int* in_sizes, int n_in,
                              void* d_out, int out_size, void* d_ws, size_t ws_size,
                              hipStream_t stream) {
    const float* t_k_hat  = (const float*)d_in[0];  // (256,4)
    const float* c_relu   = (const float*)d_in[1];  // (2049,)
    // d_in[2] = shift : analytically -(j/64), folded into the closed form
    const float* init_val = (const float*)d_in[3];  // (1,)
    float* out = (float*)d_out;                     // (256,32,4) fp32
    double* P = (double*)d_ws;                      // 2*2049 doubles = 32.8 KB

    scan_kernel<<<1, 256, 0, stream>>>(c_relu, P);
    eval_kernel<<<OUT_TOTAL / 256, 256, 0, stream>>>(t_k_hat, init_val, P, out);
}

// Round 2
// 60.329 us; speedup vs baseline: 1.0458x; 1.0458x over previous
//
#include <hip/hip_runtime.h>
#include <hip/hip_bf16.h>

// Problem constants (from reference)
#define NN 32
#define K_TOTAL 4
#define RESOLUTION 64
#define KNOTS (NN * RESOLUTION + 1)   // 2049
#define BATCH 256
#define HEAD 2048                      // KNOTS - 1; last c_eff element never contributes
#define OUT_TOTAL (BATCH * NN * K_TOTAL)  // 32768

// Single fused kernel. Closed form:
//   out[b,n,k] = r*P1[m] - P2[m]/64 + init_val
// where r = mod(t[b,k] - n, 32)  (bit-exact to np.remainder's fp32 path),
//       m = #{ j in [0,2048) : j < 64*r }  (64*r exact: power-of-two scale),
//       P1[m] = sum_{j<m} c[j],  P2[m] = sum_{j<m} j*c[j].
// The last c_eff element (index 2048, -sum(head)) never fires: its ReLU arg
// is r - 32 <= 0.
//
// Each block builds the fp32 prefix tables redundantly in its own LDS
// (removes the cross-kernel dependency that serialized R0), then evaluates
// 256 outputs. 128 blocks cover all 32768 outputs.
__global__ __launch_bounds__(256) void fused_kernel(const float* __restrict__ t_k,
                                                    const float* __restrict__ c_relu,
                                                    const float* __restrict__ init_val,
                                                    float* __restrict__ out) {
    __shared__ float P1[KNOTS];
    __shared__ float P2[KNOTS];
    __shared__ float tot1[256];
    __shared__ float tot2[256];

    const int t = threadIdx.x;
    const int base = t * 8;   // 256 threads * 8 = 2048 head elements

    // coalesced float4 loads of the head coefficients
    const float4* __restrict__ c4 = (const float4*)c_relu;
    const float4 ca = c4[2 * t];
    const float4 cb = c4[2 * t + 1];
    float c[8] = {ca.x, ca.y, ca.z, ca.w, cb.x, cb.y, cb.z, cb.w};

    // thread-local exclusive prefixes
    float pre1[8], pre2[8];
    float l1 = 0.0f, l2 = 0.0f;
#pragma unroll
    for (int i = 0; i < 8; ++i) {
        pre1[i] = l1;
        pre2[i] = l2;
        l1 += c[i];
        l2 += (float)(base + i) * c[i];
    }
    tot1[t] = l1;
    tot2[t] = l2;

    // Hillis-Steele inclusive scan over the 256 chunk totals
    for (int off = 1; off < 256; off <<= 1) {
        __syncthreads();
        float a1 = 0.0f, a2 = 0.0f;
        if (t >= off) { a1 = tot1[t - off]; a2 = tot2[t - off]; }
        __syncthreads();
        if (t >= off) { tot1[t] += a1; tot2[t] += a2; }
    }
    __syncthreads();

    const float off1 = (t == 0) ? 0.0f : tot1[t - 1];
    const float off2 = (t == 0) ? 0.0f : tot2[t - 1];
#pragma unroll
    for (int i = 0; i < 8; ++i) {
        P1[base + i] = off1 + pre1[i];
        P2[base + i] = off2 + pre2[i];
    }
    if (t == 255) {
        P1[HEAD] = tot1[255];
        P2[HEAD] = tot2[255];
    }
    __syncthreads();

    // evaluate this block's 256 outputs
    const int o = blockIdx.x * 256 + t;        // 0..32767
    const int k = o & (K_TOTAL - 1);
    const int n = (o >> 2) & (NN - 1);
    const int b = o >> 7;

    const float tv = t_k[(b << 2) | k];
    float r = tv - (float)n;                   // same single fp32 subtract as ref
    if (r < 0.0f) r += 32.0f;                  // np.remainder correction, one rounding

    const float d = r * 64.0f;                 // exact (power-of-two scale)
    int m = (int)d;
    if ((float)m < d) ++m;                     // m = ceil(d), strict j < d
    if (m > HEAD) m = HEAD;                    // safety clamp

    out[o] = r * P1[m] - P2[m] * 0.015625f + init_val[0];
}

extern "C" void kernel_launch(void* const* d_in, const int* in_sizes, int n_in,
                              void* d_out, int out_size, void* d_ws, size_t ws_size,
                              hipStream_t stream) {
    const float* t_k_hat  = (const float*)d_in[0];  // (256,4)
    const float* c_relu   = (const float*)d_in[1];  // (2049,)
    // d_in[2] = shift : analytically -(j/64), folded into the closed form
    const float* init_val = (const float*)d_in[3];  // (1,)
    float* out = (float*)d_out;                     // (256,32,4) fp32

    fused_kernel<<<OUT_TOTAL / 256, 256, 0, stream>>>(t_k_hat, c_relu, init_val, out);
}

// Round 3
// 60.047 us; speedup vs baseline: 1.0507x; 1.0047x over previous
//
#include <hip/hip_runtime.h>
#include <hip/hip_bf16.h>

// Problem constants (from reference)
#define NN 32
#define K_TOTAL 4
#define RESOLUTION 64
#define KNOTS (NN * RESOLUTION + 1)   // 2049
#define BATCH 256
#define HEAD 2048                      // KNOTS - 1; last c_eff element never contributes
#define OUT_TOTAL (BATCH * NN * K_TOTAL)  // 32768

// Single fused kernel. Closed form:
//   out[b,n,k] = r*P1[m] - P2[m]/64 + init_val
// where r = mod(t[b,k] - n, 32)  (bit-exact to np.remainder's fp32 path),
//       m = #{ j in [0,2048) : j < 64*r }  (64*r exact: power-of-two scale),
//       P1[m] = sum_{j<m} c[j],  P2[m] = sum_{j<m} j*c[j].
// The c_eff tail element (index 2048, -sum(head)) never fires: ReLU arg <= 0.
//
// Scan strategy (R2): per-wave __shfl_up inclusive scan (no barriers) +
// one cross-wave LDS combine -> 2 __syncthreads total (R1 had 17).
// Accumulation in fp64 to kill the 2048-term cancellation error seen in R1
// (absmax 0.0156 -> ~1e-5); tables stored fp32 for the cheap eval.
__global__ __launch_bounds__(256) void fused_kernel(const float* __restrict__ t_k,
                                                    const float* __restrict__ c_relu,
                                                    const float* __restrict__ init_val,
                                                    float* __restrict__ out) {
    __shared__ float P1[KNOTS];
    __shared__ float P2[KNOTS];
    __shared__ double w1[4];
    __shared__ double w2[4];

    const int t = threadIdx.x;
    const int lane = t & 63;
    const int wave = t >> 6;
    const int base = t * 8;   // 256 threads * 8 = 2048 head elements

    // coalesced float4 loads of the head coefficients
    const float4* __restrict__ c4 = (const float4*)c_relu;
    const float4 ca = c4[2 * t];
    const float4 cb = c4[2 * t + 1];
    const float c[8] = {ca.x, ca.y, ca.z, ca.w, cb.x, cb.y, cb.z, cb.w};

    // thread-local exclusive prefixes (fp64)
    double pre1[8], pre2[8];
    double l1 = 0.0, l2 = 0.0;
#pragma unroll
    for (int i = 0; i < 8; ++i) {
        pre1[i] = l1;
        pre2[i] = l2;
        l1 += (double)c[i];
        l2 += (double)(base + i) * (double)c[i];
    }
    const double own1 = l1, own2 = l2;

    // wave-level inclusive scan over the 64 chunk totals (no barriers)
#pragma unroll
    for (int d = 1; d < 64; d <<= 1) {
        const double y1 = __shfl_up(l1, d);
        const double y2 = __shfl_up(l2, d);
        if (lane >= d) { l1 += y1; l2 += y2; }
    }

    // cross-wave combine: lane 63 publishes wave totals
    if (lane == 63) { w1[wave] = l1; w2[wave] = l2; }
    __syncthreads();   // barrier 1

    double woff1 = 0.0, woff2 = 0.0;
#pragma unroll
    for (int w = 0; w < 3; ++w) {
        if (wave > w) { woff1 += w1[w]; woff2 += w2[w]; }
    }

    // exclusive offset for this thread's chunk
    const double off1 = woff1 + (l1 - own1);
    const double off2 = woff2 + (l2 - own2);

#pragma unroll
    for (int i = 0; i < 8; ++i) {
        P1[base + i] = (float)(off1 + pre1[i]);
        P2[base + i] = (float)(off2 + pre2[i]);
    }
    if (t == 255) {   // grand totals -> last table entry
        P1[HEAD] = (float)(woff1 + l1);
        P2[HEAD] = (float)(woff2 + l2);
    }
    __syncthreads();   // barrier 2

    // evaluate this block's 256 outputs
    const int o = blockIdx.x * 256 + t;        // 0..32767
    const int k = o & (K_TOTAL - 1);
    const int n = (o >> 2) & (NN - 1);
    const int b = o >> 7;

    const float tv = t_k[(b << 2) | k];
    float r = tv - (float)n;                   // same single fp32 subtract as ref
    if (r < 0.0f) r += 32.0f;                  // np.remainder correction, one rounding

    const float d = r * 64.0f;                 // exact (power-of-two scale)
    int m = (int)d;
    if ((float)m < d) ++m;                     // m = ceil(d): strict j < d
    if (m > HEAD) m = HEAD;                    // safety clamp

    out[o] = r * P1[m] - P2[m] * 0.015625f + init_val[0];
}

extern "C" void kernel_launch(void* const* d_in, const int* in_sizes, int n_in,
                              void* d_out, int out_size, void* d_ws, size_t ws_size,
                              hipStream_t stream) {
    const float* t_k_hat  = (const float*)d_in[0];  // (256,4)
    const float* c_relu   = (const float*)d_in[1];  // (2049,)
    // d_in[2] = shift : analytically -(j/64), folded into the closed form
    const float* init_val = (const float*)d_in[3];  // (1,)
    float* out = (float*)d_out;                     // (256,32,4) fp32

    fused_kernel<<<OUT_TOTAL / 256, 256, 0, stream>>>(t_k_hat, c_relu, init_val, out);
}